// Round 10
// baseline (57.174 us; speedup 1.0000x reference)
//
#include <hip/hip_runtime.h>
#include <math.h>

#define BB 64
#define NN 8192
#define TOTAL_W 9356

typedef _Float16 f16x8 __attribute__((ext_vector_type(8)));
typedef float f32x4 __attribute__((ext_vector_type(4)));
typedef float f32x2 __attribute__((ext_vector_type(2)));
typedef unsigned int u32x2 __attribute__((ext_vector_type(2)));
typedef unsigned int u32x4 __attribute__((ext_vector_type(4)));

#define L2E 1.44269504088896340736f
#define LN2 0.6931471805599453f

// ---- ws layout (bytes, per b) ----
#define WS_FILM 0        // film2: [4 l][16 quad][{bias4,wsc4*L2E,bsc4*L2E,wsh4}] = 4096
#define WS_A1   4096     // A-frags L1 = 8192
#define WS_A2   12288    // A-frags L2 = 8192
#define WS_A0   20480    // A0 frag image [4 m][64 lane] f16x8 = 4096
#define WS_A3   24576    // A3 frag image [2 t][64 lane] f16x8 = 2048
#define WSB     26624

// ---- LDS layout (bytes) ----
#define A1_OFF    0                     // 8192
#define A2_OFF    8192                  // 8192
#define ACT_OFF   16384                 // Act[16 slots][128 pts] x 8B, column-major = 16384
#define LDS_BYTES 32768                 // 5 blocks/CU (5*32768 = 163840 exactly)

#define MFMA16(a, b, c) __builtin_amdgcn_mfma_f32_16x16x32_f16(a, b, c, 0, 0, 0)
#define EXP2 __builtin_amdgcn_exp2f
#define LOG2 __builtin_amdgcn_logf
#define RCPF __builtin_amdgcn_rcpf

__device__ __forceinline__ f32x2 pfma(f32x2 a, f32x2 b, f32x2 c) {
  return __builtin_elementwise_fma(a, b, c);
}

// film params now read straight from global ws (L1/L2-resident)
__device__ __forceinline__ const f32x4* film_base(const unsigned char* wsb, int l, int qd) {
  return (const f32x4*)(wsb + WS_FILM + ((l * 16 + qd) << 6));
}

// FiLM (+softplus) on a D-quad for one point; acc already includes bias.
template<bool SP>
__device__ __forceinline__ u32x2 film_quad(f32x4 acc, float ctx,
                                           f32x4 wscq, f32x4 bscq, f32x4 wshq) {
  f32x2 ctx2 = {ctx, ctx};
  f32x2 one = {1.f, 1.f};
  f32x2 z0 = pfma(ctx2, (f32x2){wscq.x, wscq.y}, (f32x2){bscq.x, bscq.y});
  f32x2 z1 = pfma(ctx2, (f32x2){wscq.z, wscq.w}, (f32x2){bscq.z, bscq.w});
  f32x2 d0 = {EXP2(-z0.x), EXP2(-z0.y)};  d0 += one;
  f32x2 d1 = {EXP2(-z1.x), EXP2(-z1.y)};  d1 += one;
  f32x2 s0 = {RCPF(d0.x), RCPF(d0.y)};
  f32x2 s1 = {RCPF(d1.x), RCPF(d1.y)};
  f32x2 v0 = pfma(ctx2, (f32x2){wshq.x, wshq.y}, s0 * (f32x2){acc.x, acc.y});
  f32x2 v1 = pfma(ctx2, (f32x2){wshq.z, wshq.w}, s1 * (f32x2){acc.z, acc.w});
  if (SP) {  // softplus = LN2 * log2(1 + 2^(v*L2E))
    f32x2 l2 = {L2E, L2E}, ln = {LN2, LN2};
    f32x2 t0 = v0 * l2, t1 = v1 * l2;
    f32x2 u0 = {EXP2(t0.x), EXP2(t0.y)};  u0 += one;
    f32x2 u1 = {EXP2(t1.x), EXP2(t1.y)};  u1 += one;
    f32x2 g0 = {LOG2(u0.x), LOG2(u0.y)};
    f32x2 g1 = {LOG2(u1.x), LOG2(u1.y)};
    v0 = g0 * ln;
    v1 = g1 * ln;
  }
  auto p01 = __builtin_amdgcn_cvt_pkrtz(v0.x, v0.y);
  auto p23 = __builtin_amdgcn_cvt_pkrtz(v1.x, v1.y);
  u32x2 w;
  w.x = __builtin_bit_cast(unsigned int, p01);
  w.y = __builtin_bit_cast(unsigned int, p23);
  return w;
}

// Act column-major: slot s (feats 4s..4s+3) of point pt at ACT_OFF + s*1024 + pt*8.
// Store: one base reg, per-m immediate offsets. Banks optimal (32x4 per 512B store).
__device__ __forceinline__ void act_store(unsigned char* smem, int pt, int slot, u32x2 w) {
  *(u32x2*)(smem + ACT_OFF + (slot << 10) + (pt << 3)) = w;
}
// Load pair q (feats 8q..8q+7): rows 2q and 2q+1, same column pt.
__device__ __forceinline__ f16x8 act_load(const unsigned char* smem, int pt, int pair) {
  u32x2 lo = *(const u32x2*)(smem + ACT_OFF + ((2 * pair) << 10) + (pt << 3));
  u32x2 hi = *(const u32x2*)(smem + ACT_OFF + ((2 * pair + 1) << 10) + (pt << 3));
  u32x4 v = {lo.x, lo.y, hi.x, hi.y};
  return __builtin_bit_cast(f16x8, v);
}

// ============ prep kernel: one block per b, builds ws images ============
__global__ __launch_bounds__(512)
void ode_prep_kernel(const float* __restrict__ tnw, unsigned char* __restrict__ ws) {
  const int b = blockIdx.x;
  const int tid = threadIdx.x;
  const float* __restrict__ wb = tnw + (size_t)b * TOTAL_W;
  unsigned char* __restrict__ wsb = ws + (size_t)b * WSB;

  // film2 params; layer l: bias@bo, wsc@bo+d, bsc@bo+2d, wsh@bo+3d
  if (tid < 64) {
    const int biaso[4] = {192, 4544, 8896, 9344};
    const int dim[4] = {64, 64, 64, 3};
#pragma unroll
    for (int l = 0; l < 4; ++l) {
      float bv = 0.f, wscv = 0.f, bscv = 0.f, wshv = 0.f;
      if (tid < dim[l]) {
        int bo = biaso[l], d = dim[l];
        bv = wb[bo + tid];
        wscv = wb[bo + d + tid] * L2E;
        bscv = wb[bo + 2 * d + tid] * L2E;
        wshv = wb[bo + 3 * d + tid];
      }
      float* f2 = (float*)(wsb + WS_FILM + ((l * 16 + (tid >> 2)) << 6)) + (tid & 3);
      f2[0] = bv;
      f2[4] = wscv;
      f2[8] = bscv;
      f2[12] = wshv;
    }
  }
  // A-fragments L1/L2 (A = W^T): row r = m*128 + t*64 + lane.
  // lane holds A[row=lane&15][k=8*(lane>>4)+i]: f_out=16m+(lane&15), f_in=32t+8*(lane>>4)+i
#pragma unroll
  for (int L = 0; L < 2; ++L) {
    const int woff = L ? 4800 : 448;
    unsigned char* dst = wsb + (L ? WS_A2 : WS_A1);
    int r = tid;  // 512 threads, 512 rows
    int lane_r = r & 63;
    int t = (r >> 6) & 1;
    int m = r >> 7;
    int f_out = 16 * m + (lane_r & 15);
    int f_in0 = 32 * t + 8 * (lane_r >> 4);
    f16x8 h;
#pragma unroll
    for (int i = 0; i < 8; ++i) h[i] = (_Float16)wb[woff + (f_in0 + i) * 64 + f_out];
    *(f16x8*)(dst + r * 16) = h;
  }
  // A0 register image: [m][lane], lane=(g,col); k=0..2 live in g==0
  if (tid < 256) {
    int m = tid >> 6;
    int lane = tid & 63;
    int g = lane >> 4, col = lane & 15;
    f16x8 h = {0, 0, 0, 0, 0, 0, 0, 0};
    if (g == 0) {
#pragma unroll
      for (int i = 0; i < 3; ++i) h[i] = (_Float16)wb[i * 64 + 16 * m + col];
    }
    *(f16x8*)(wsb + WS_A0 + tid * 16) = h;
  }
  // A3 register image: [t][lane]
  if (tid < 128) {
    int t = tid >> 6;
    int lane = tid & 63;
    int g = lane >> 4, col = lane & 15;
    f16x8 h = {0, 0, 0, 0, 0, 0, 0, 0};
    if (col < 3) {
#pragma unroll
      for (int i = 0; i < 8; ++i)
        h[i] = (_Float16)wb[9152 + (32 * t + 8 * g + i) * 3 + col];
    }
    *(f16x8*)(wsb + WS_A3 + tid * 16) = h;
  }
}

// ============ main kernel ============
__global__ __launch_bounds__(256)
void ode_hypernet_kernel(const float* __restrict__ context,
                         const float* __restrict__ y,
                         const unsigned char* __restrict__ ws,
                         float* __restrict__ out) {
  __shared__ __align__(16) unsigned char smem[LDS_BYTES];
  const int b = blockIdx.y;
  const int tid = threadIdx.x;
  const unsigned char* __restrict__ wsb = ws + (size_t)b * WSB;

  const int lane = tid & 63;
  const int wid = tid >> 6;
  const int g = lane >> 4;
  const int col = lane & 15;

  // ---------- staging: linear coalesced copy of A1+A2 (16 KB) ----------
#pragma unroll
  for (int it = 0; it < 4; ++it) {
    int i = tid + it * 256;  // i < 1024
    *(f32x4*)(smem + i * 16) = *(const f32x4*)(wsb + WS_A1 + i * 16);
  }
  // register fragments straight from ws (16B coalesced loads)
  f16x8 A0r[4];
#pragma unroll
  for (int m = 0; m < 4; ++m)
    A0r[m] = *(const f16x8*)(wsb + WS_A0 + (m * 64 + lane) * 16);
  f16x8 A3r0 = *(const f16x8*)(wsb + WS_A3 + lane * 16);
  f16x8 A3r1 = *(const f16x8*)(wsb + WS_A3 + (64 + lane) * 16);
  __syncthreads();

  // ---------- per-wave main ----------
  const int pt0 = wid * 32 + col;  // 0..127
  const int pt1 = pt0 + 16;

  // hoist both supersteps' inputs
  const int nb = blockIdx.x * 256;
  const size_t cb = (size_t)b * NN;
  float ctxs[4], yv[4][3];
#pragma unroll
  for (int k = 0; k < 4; ++k) {  // k = ss*2 + (pt1?1:0)
    int n = nb + (k >> 1) * 128 + pt0 + (k & 1) * 16;
    ctxs[k] = context[cb + n];
    const float* yp = y + (cb + n) * 3;
    yv[k][0] = yp[0]; yv[k][1] = yp[1]; yv[k][2] = yp[2];
  }

#pragma unroll
  for (int ss = 0; ss < 2; ++ss) {
    const float ctx0 = ctxs[ss * 2], ctx1 = ctxs[ss * 2 + 1];
    const int n0 = nb + ss * 128 + pt0;
    const int n1 = n0 + 16;

    // B-fragments for layer 0 from y (k=0..2 live in g==0 lanes)
    f16x8 By0 = {0, 0, 0, 0, 0, 0, 0, 0};
    f16x8 By1 = {0, 0, 0, 0, 0, 0, 0, 0};
    if (g == 0) {
      By0[0] = (_Float16)yv[ss * 2][0];
      By0[1] = (_Float16)yv[ss * 2][1];
      By0[2] = (_Float16)yv[ss * 2][2];
      By1[0] = (_Float16)yv[ss * 2 + 1][0];
      By1[1] = (_Float16)yv[ss * 2 + 1][1];
      By1[2] = (_Float16)yv[ss * 2 + 1][2];
    }

    // ----- layer 0 (3 -> 64) on MFMA (single k-tile) -----
#pragma unroll
    for (int m = 0; m < 4; ++m) {
      const f32x4* fb = film_base(wsb, 0, 4 * m + g);
      f32x4 biasq = fb[0], wscq = fb[1], bscq = fb[2], wshq = fb[3];
      f32x4 c0 = biasq, c1 = biasq;
      c0 = MFMA16(A0r[m], By0, c0);
      c1 = MFMA16(A0r[m], By1, c1);
      act_store(smem, pt0, 4 * m + g, film_quad<true>(c0, ctx0, wscq, bscq, wshq));
      act_store(smem, pt1, 4 * m + g, film_quad<true>(c1, ctx1, wscq, bscq, wshq));
    }

    // ----- layers 1,2 (64 -> 64) on MFMA -----
#pragma unroll
    for (int L = 1; L <= 2; ++L) {
      const int aoff = (L == 1) ? A1_OFF : A2_OFF;
      f16x8 B00 = act_load(smem, pt0, g);
      f16x8 B01 = act_load(smem, pt0, 4 + g);
      f16x8 B10 = act_load(smem, pt1, g);
      f16x8 B11 = act_load(smem, pt1, 4 + g);
#pragma unroll
      for (int m = 0; m < 4; ++m) {
        const f32x4* fb = film_base(wsb, L, 4 * m + g);
        f32x4 biasq = fb[0], wscq = fb[1], bscq = fb[2], wshq = fb[3];
        f16x8 a0 = *(const f16x8*)(smem + aoff + ((m * 2 + 0) * 64 + lane) * 16);
        f16x8 a1 = *(const f16x8*)(smem + aoff + ((m * 2 + 1) * 64 + lane) * 16);
        f32x4 c0 = biasq, c1 = biasq;
        c0 = MFMA16(a0, B00, c0);
        c0 = MFMA16(a1, B01, c0);
        c1 = MFMA16(a0, B10, c1);
        c1 = MFMA16(a1, B11, c1);
        act_store(smem, pt0, 4 * m + g, film_quad<true>(c0, ctx0, wscq, bscq, wshq));
        act_store(smem, pt1, 4 * m + g, film_quad<true>(c1, ctx1, wscq, bscq, wshq));
      }
    }

    // ----- layer 3 (64 -> 3) on MFMA (A from regs), FiLM only -----
    {
      f16x8 B00 = act_load(smem, pt0, g);
      f16x8 B01 = act_load(smem, pt0, 4 + g);
      f16x8 B10 = act_load(smem, pt1, g);
      f16x8 B11 = act_load(smem, pt1, 4 + g);
      const f32x4* fb = film_base(wsb, 3, g);
      f32x4 biasq = fb[0], wscq = fb[1], bscq = fb[2], wshq = fb[3];
      f32x4 c0 = biasq, c1 = biasq;
      c0 = MFMA16(A3r0, B00, c0);
      c0 = MFMA16(A3r1, B01, c0);
      c1 = MFMA16(A3r0, B10, c1);
      c1 = MFMA16(A3r1, B11, c1);
      if (g == 0) {
#pragma unroll
        for (int p = 0; p < 2; ++p) {
          f32x4 c = p ? c1 : c0;
          float ctx = p ? ctx1 : ctx0;
          int n = p ? n1 : n0;
#pragma unroll
          for (int j = 0; j < 3; ++j) {
            float z = fmaf(ctx, wscq[j], bscq[j]);
            float s = RCPF(1.0f + EXP2(-z));
            float v = fmaf(ctx, wshq[j], s * c[j]);
            out[((size_t)b * NN + n) * 3 + j] = v;
          }
        }
      }
    }
  }
}

extern "C" void kernel_launch(void* const* d_in, const int* in_sizes, int n_in,
                              void* d_out, int out_size, void* d_ws, size_t ws_size,
                              hipStream_t stream) {
  const float* context = (const float*)d_in[0];  // (64, 8192)
  const float* y       = (const float*)d_in[1];  // (64, 8192, 3)
  const float* tnw     = (const float*)d_in[2];  // (64, 9356)
  float* out           = (float*)d_out;          // (64, 8192, 3)
  unsigned char* ws    = (unsigned char*)d_ws;   // needs 64*26624 = 1,703,936 B

  ode_prep_kernel<<<dim3(BB, 1, 1), dim3(512, 1, 1), 0, stream>>>(tnw, ws);
  dim3 grid(NN / 256, BB, 1);  // 2048 blocks, 256 points each (2 ss x 128)
  dim3 block(256, 1, 1);
  ode_hypernet_kernel<<<grid, block, 0, stream>>>(context, y, ws, out);
}

// Round 11
// 56.079 us; speedup vs baseline: 1.0195x; 1.0195x over previous
//
#include <hip/hip_runtime.h>
#include <math.h>

#define BB 64
#define NN 8192
#define TOTAL_W 9356

typedef _Float16 f16x4 __attribute__((ext_vector_type(4)));
typedef float f32x4 __attribute__((ext_vector_type(4)));
typedef float f32x2 __attribute__((ext_vector_type(2)));
typedef unsigned int u32x2 __attribute__((ext_vector_type(2)));

#define L2E 1.44269504088896340736f
#define LN2 0.6931471805599453f

// ---- ws layout (bytes, per b) ----
#define WS_FILM 0        // film2: [4 l][16 quad][{bias4,wsc4*L2E,bsc4*L2E,wsh4}] = 4096
#define WS_A1   4096     // A-tiles L1: [m][t][lane] f16x4 = 8192
#define WS_A2   12288    // A-tiles L2 = 8192
#define WS_A0   20480    // A0 tile image [4 m][64 lane] f16x4 = 2048
#define WS_A3   22528    // A3 tile image [4 t][64 lane] f16x4 = 2048
#define WSB     24576

// ---- LDS layout (bytes): verbatim copy of ws[0..20480) ----
#define FILM2_OFF 0
#define A1_OFF    4096
#define A2_OFF    12288
#define LDS_BYTES 20480                 // 8 blocks/CU (8*20480 = 163840 exactly)

#if __has_builtin(__builtin_amdgcn_mfma_f32_16x16x16_f16)
#define MFMAK16(a, b, c) __builtin_amdgcn_mfma_f32_16x16x16_f16(a, b, c, 0, 0, 0)
#else
#define MFMAK16(a, b, c) __builtin_amdgcn_mfma_f32_16x16x16f16(a, b, c, 0, 0, 0)
#endif
#define EXP2 __builtin_amdgcn_exp2f
#define LOG2 __builtin_amdgcn_logf
#define RCPF __builtin_amdgcn_rcpf

__device__ __forceinline__ f32x2 pfma(f32x2 a, f32x2 b, f32x2 c) {
  return __builtin_elementwise_fma(a, b, c);
}

__device__ __forceinline__ const f32x4* film_base(const unsigned char* smem, int l, int qd) {
  return (const f32x4*)(smem + FILM2_OFF + ((l * 16 + qd) << 6));
}

// FiLM (+softplus) on a D-quad; acc includes bias. Returns packed f16x4
// (rows 4g..4g+3 of m-tile) == B operand dwords for next layer's k-tile.
template<bool SP>
__device__ __forceinline__ f16x4 film_quad(f32x4 acc, float ctx,
                                           f32x4 wscq, f32x4 bscq, f32x4 wshq) {
  f32x2 ctx2 = {ctx, ctx};
  f32x2 one = {1.f, 1.f};
  f32x2 z0 = pfma(ctx2, (f32x2){wscq.x, wscq.y}, (f32x2){bscq.x, bscq.y});
  f32x2 z1 = pfma(ctx2, (f32x2){wscq.z, wscq.w}, (f32x2){bscq.z, bscq.w});
  f32x2 d0 = {EXP2(-z0.x), EXP2(-z0.y)};  d0 += one;
  f32x2 d1 = {EXP2(-z1.x), EXP2(-z1.y)};  d1 += one;
  f32x2 s0 = {RCPF(d0.x), RCPF(d0.y)};
  f32x2 s1 = {RCPF(d1.x), RCPF(d1.y)};
  f32x2 v0 = pfma(ctx2, (f32x2){wshq.x, wshq.y}, s0 * (f32x2){acc.x, acc.y});
  f32x2 v1 = pfma(ctx2, (f32x2){wshq.z, wshq.w}, s1 * (f32x2){acc.z, acc.w});
  if (SP) {  // softplus = LN2 * log2(1 + 2^(v*L2E))
    f32x2 l2 = {L2E, L2E}, ln = {LN2, LN2};
    f32x2 t0 = v0 * l2, t1 = v1 * l2;
    f32x2 u0 = {EXP2(t0.x), EXP2(t0.y)};  u0 += one;
    f32x2 u1 = {EXP2(t1.x), EXP2(t1.y)};  u1 += one;
    f32x2 g0 = {LOG2(u0.x), LOG2(u0.y)};
    f32x2 g1 = {LOG2(u1.x), LOG2(u1.y)};
    v0 = g0 * ln;
    v1 = g1 * ln;
  }
  auto p01 = __builtin_amdgcn_cvt_pkrtz(v0.x, v0.y);
  auto p23 = __builtin_amdgcn_cvt_pkrtz(v1.x, v1.y);
  u32x2 w;
  w.x = __builtin_bit_cast(unsigned int, p01);
  w.y = __builtin_bit_cast(unsigned int, p23);
  return __builtin_bit_cast(f16x4, w);
}

// A-tile read: layer base aoff, tile (m,t), per-lane f16x4 (8B)
__device__ __forceinline__ f16x4 a_tile(const unsigned char* smem, int aoff,
                                        int m, int t, int lane) {
  return *(const f16x4*)(smem + aoff + (((m * 4 + t) * 64 + lane) << 3));
}

// ============ prep kernel: one block per b, builds ws images ============
__global__ __launch_bounds__(512)
void ode_prep_kernel(const float* __restrict__ tnw, unsigned char* __restrict__ ws) {
  const int b = blockIdx.x;
  const int tid = threadIdx.x;
  const float* __restrict__ wb = tnw + (size_t)b * TOTAL_W;
  unsigned char* __restrict__ wsb = ws + (size_t)b * WSB;

  // film2 params; layer l: bias@bo, wsc@bo+d, bsc@bo+2d, wsh@bo+3d
  if (tid < 64) {
    const int biaso[4] = {192, 4544, 8896, 9344};
    const int dim[4] = {64, 64, 64, 3};
#pragma unroll
    for (int l = 0; l < 4; ++l) {
      float bv = 0.f, wscv = 0.f, bscv = 0.f, wshv = 0.f;
      if (tid < dim[l]) {
        int bo = biaso[l], d = dim[l];
        bv = wb[bo + tid];
        wscv = wb[bo + d + tid] * L2E;
        bscv = wb[bo + 2 * d + tid] * L2E;
        wshv = wb[bo + 3 * d + tid];
      }
      float* f2 = (float*)(wsb + WS_FILM + ((l * 16 + (tid >> 2)) << 6)) + (tid & 3);
      f2[0] = bv;
      f2[4] = wscv;
      f2[8] = bscv;
      f2[12] = wshv;
    }
  }
  // A-tiles L1/L2 (A = W^T, 16x16): entry idx = tile(m,t)*64 + lane.
  // lane: row = lane&15 -> f_out = 16m+row; k0 = 4*(lane>>4) -> f_in = 16t+k0+i
#pragma unroll
  for (int L = 0; L < 2; ++L) {
    const int woff = L ? 4800 : 448;
    unsigned char* dst = wsb + (L ? WS_A2 : WS_A1);
#pragma unroll
    for (int it = 0; it < 2; ++it) {
      int idx = tid + it * 512;          // < 1024
      int lane = idx & 63;
      int tile = idx >> 6;               // m*4 + t
      int m = tile >> 2, t = tile & 3;
      int f_out = 16 * m + (lane & 15);
      int f_in0 = 16 * t + 4 * (lane >> 4);
      f16x4 h;
#pragma unroll
      for (int i = 0; i < 4; ++i) h[i] = (_Float16)wb[woff + (f_in0 + i) * 64 + f_out];
      *(f16x4*)(dst + idx * 8) = h;
    }
  }
  // A0 tile image [m][lane]: W0 3x64; k = 4*(lane>>4)+i, live only lane>>4==0, i<3
  if (tid < 256) {
    int m = tid >> 6;
    int lane = tid & 63;
    int kg = lane >> 4, row = lane & 15;
    f16x4 h = {0, 0, 0, 0};
    if (kg == 0) {
#pragma unroll
      for (int i = 0; i < 3; ++i) h[i] = (_Float16)wb[i * 64 + 16 * m + row];
    }
    *(f16x4*)(wsb + WS_A0 + tid * 8) = h;
  }
  // A3 tile image [t][lane]: W3 64x3; f_out = lane&15 (rows >=3 zero), f_in = 16t+4kg+i
  if (tid < 256) {
    int t = tid >> 6;
    int lane = tid & 63;
    int kg = lane >> 4, row = lane & 15;
    f16x4 h = {0, 0, 0, 0};
    if (row < 3) {
#pragma unroll
      for (int i = 0; i < 4; ++i)
        h[i] = (_Float16)wb[9152 + (16 * t + 4 * kg + i) * 3 + row];
    }
    *(f16x4*)(wsb + WS_A3 + tid * 8) = h;
  }
}

// ============ main kernel ============
__global__ __launch_bounds__(256)
void ode_hypernet_kernel(const float* __restrict__ context,
                         const float* __restrict__ y,
                         const unsigned char* __restrict__ ws,
                         float* __restrict__ out) {
  __shared__ __align__(16) unsigned char smem[LDS_BYTES];
  const int b = blockIdx.y;
  const int tid = threadIdx.x;
  const unsigned char* __restrict__ wsb = ws + (size_t)b * WSB;

  const int lane = tid & 63;
  const int wid = tid >> 6;
  const int g = lane >> 4;
  const int col = lane & 15;

  // ---------- staging: linear coalesced copy of film2+A1+A2 (20 KB) ----------
#pragma unroll
  for (int it = 0; it < 5; ++it) {
    int i = tid + it * 256;  // i < 1280
    *(f32x4*)(smem + i * 16) = *(const f32x4*)(wsb + i * 16);
  }
  // A0/A3 tiles -> registers (8B coalesced loads)
  f16x4 A0r[4], A3r[4];
#pragma unroll
  for (int m = 0; m < 4; ++m)
    A0r[m] = *(const f16x4*)(wsb + WS_A0 + ((m * 64 + lane) << 3));
#pragma unroll
  for (int t = 0; t < 4; ++t)
    A3r[t] = *(const f16x4*)(wsb + WS_A3 + ((t * 64 + lane) << 3));
  __syncthreads();

  // ---------- per-wave main (all activations in registers) ----------
  const int pt0 = wid * 32 + col;  // 0..127
  const int nb = blockIdx.x * 256;
  const size_t cb = (size_t)b * NN;

  float ctxs[4], yv[4][3];
#pragma unroll
  for (int k = 0; k < 4; ++k) {  // k = ss*2 + grp
    int n = nb + (k >> 1) * 128 + pt0 + (k & 1) * 16;
    ctxs[k] = context[cb + n];
    const float* yp = y + (cb + n) * 3;
    yv[k][0] = yp[0]; yv[k][1] = yp[1]; yv[k][2] = yp[2];
  }

#pragma unroll
  for (int ss = 0; ss < 2; ++ss) {
    const float ctx0 = ctxs[ss * 2], ctx1 = ctxs[ss * 2 + 1];
    const int n0 = nb + ss * 128 + pt0;
    const int n1 = n0 + 16;

    // Layer-0 B operand from y: k = 4g+i, live only g==0, i<3
    f16x4 By0 = {0, 0, 0, 0}, By1 = {0, 0, 0, 0};
    if (g == 0) {
      By0[0] = (_Float16)yv[ss * 2][0];
      By0[1] = (_Float16)yv[ss * 2][1];
      By0[2] = (_Float16)yv[ss * 2][2];
      By1[0] = (_Float16)yv[ss * 2 + 1][0];
      By1[1] = (_Float16)yv[ss * 2 + 1][1];
      By1[2] = (_Float16)yv[ss * 2 + 1][2];
    }

    f16x4 Bc0[4], Bc1[4], Bd0[4], Bd1[4];

    // ----- layer 0 (3 -> 64): one K=16 MFMA per m-tile -----
#pragma unroll
    for (int m = 0; m < 4; ++m) {
      const f32x4* fb = film_base(smem, 0, 4 * m + g);
      f32x4 biasq = fb[0], wscq = fb[1], bscq = fb[2], wshq = fb[3];
      f32x4 c0 = biasq, c1 = biasq;
      c0 = MFMAK16(A0r[m], By0, c0);
      c1 = MFMAK16(A0r[m], By1, c1);
      Bc0[m] = film_quad<true>(c0, ctx0, wscq, bscq, wshq);
      Bc1[m] = film_quad<true>(c1, ctx1, wscq, bscq, wshq);
    }

    // ----- layer 1 (64 -> 64): Bc -> Bd -----
#pragma unroll
    for (int m = 0; m < 4; ++m) {
      const f32x4* fb = film_base(smem, 1, 4 * m + g);
      f32x4 biasq = fb[0], wscq = fb[1], bscq = fb[2], wshq = fb[3];
      f32x4 c0 = biasq, c1 = biasq;
#pragma unroll
      for (int t = 0; t < 4; ++t) {
        f16x4 a = a_tile(smem, A1_OFF, m, t, lane);
        c0 = MFMAK16(a, Bc0[t], c0);
        c1 = MFMAK16(a, Bc1[t], c1);
      }
      Bd0[m] = film_quad<true>(c0, ctx0, wscq, bscq, wshq);
      Bd1[m] = film_quad<true>(c1, ctx1, wscq, bscq, wshq);
    }

    // ----- layer 2 (64 -> 64): Bd -> Bc -----
#pragma unroll
    for (int m = 0; m < 4; ++m) {
      const f32x4* fb = film_base(smem, 2, 4 * m + g);
      f32x4 biasq = fb[0], wscq = fb[1], bscq = fb[2], wshq = fb[3];
      f32x4 c0 = biasq, c1 = biasq;
#pragma unroll
      for (int t = 0; t < 4; ++t) {
        f16x4 a = a_tile(smem, A2_OFF, m, t, lane);
        c0 = MFMAK16(a, Bd0[t], c0);
        c1 = MFMAK16(a, Bd1[t], c1);
      }
      Bc0[m] = film_quad<true>(c0, ctx0, wscq, bscq, wshq);
      Bc1[m] = film_quad<true>(c1, ctx1, wscq, bscq, wshq);
    }

    // ----- layer 3 (64 -> 3): A from regs, FiLM only -----
    {
      const f32x4* fb = film_base(smem, 3, g);
      f32x4 biasq = fb[0], wscq = fb[1], bscq = fb[2], wshq = fb[3];
      f32x4 c0 = biasq, c1 = biasq;
#pragma unroll
      for (int t = 0; t < 4; ++t) {
        c0 = MFMAK16(A3r[t], Bc0[t], c0);
        c1 = MFMAK16(A3r[t], Bc1[t], c1);
      }
      if (g == 0) {
#pragma unroll
        for (int p = 0; p < 2; ++p) {
          f32x4 c = p ? c1 : c0;
          float ctx = p ? ctx1 : ctx0;
          int n = p ? n1 : n0;
#pragma unroll
          for (int j = 0; j < 3; ++j) {
            float z = fmaf(ctx, wscq[j], bscq[j]);
            float s = RCPF(1.0f + EXP2(-z));
            float v = fmaf(ctx, wshq[j], s * c[j]);
            out[((size_t)b * NN + n) * 3 + j] = v;
          }
        }
      }
    }
  }
}

extern "C" void kernel_launch(void* const* d_in, const int* in_sizes, int n_in,
                              void* d_out, int out_size, void* d_ws, size_t ws_size,
                              hipStream_t stream) {
  const float* context = (const float*)d_in[0];  // (64, 8192)
  const float* y       = (const float*)d_in[1];  // (64, 8192, 3)
  const float* tnw     = (const float*)d_in[2];  // (64, 9356)
  float* out           = (float*)d_out;          // (64, 8192, 3)
  unsigned char* ws    = (unsigned char*)d_ws;   // needs 64*24576 = 1,572,864 B

  ode_prep_kernel<<<dim3(BB, 1, 1), dim3(512, 1, 1), 0, stream>>>(tnw, ws);
  dim3 grid(NN / 256, BB, 1);  // 2048 blocks, 256 points each (2 ss x 128)
  dim3 block(256, 1, 1);
  ode_hypernet_kernel<<<grid, block, 0, stream>>>(context, y, ws, out);
}

// Round 12
// 55.314 us; speedup vs baseline: 1.0336x; 1.0138x over previous
//
#include <hip/hip_runtime.h>
#include <math.h>

#define BB 64
#define NN 8192
#define TOTAL_W 9356

typedef _Float16 f16x4 __attribute__((ext_vector_type(4)));
typedef float f32x4 __attribute__((ext_vector_type(4)));
typedef float f32x2 __attribute__((ext_vector_type(2)));
typedef unsigned int u32x2 __attribute__((ext_vector_type(2)));

#define L2E 1.44269504088896340736f
#define LN2 0.6931471805599453f

// ---- ws layout (bytes, per b) ----
#define WS_FILM 0        // film2: [4 l][16 quad][{bias4,wsc4,bsc4,wsh4}] prescaled = 4096
#define WS_A1   4096     // A-tiles L1: [m][t][lane] f16x4 = 8192 (unscaled: L2E*LN2=1)
#define WS_A2   12288    // A-tiles L2 = 8192
#define WS_A0   20480    // A0 tile image [4 m][64 lane] f16x4, scaled by L2E = 2048
#define WS_A3   22528    // A3 tile image [4 t][64 lane] f16x4, scaled by LN2 = 2048
#define WSB     24576

// ---- LDS layout (bytes): verbatim copy of ws[0..20480) ----
#define FILM2_OFF 0
#define A1_OFF    4096
#define A2_OFF    12288
#define LDS_BYTES 20480

#if __has_builtin(__builtin_amdgcn_mfma_f32_16x16x16_f16)
#define MFMAK16(a, b, c) __builtin_amdgcn_mfma_f32_16x16x16_f16(a, b, c, 0, 0, 0)
#else
#define MFMAK16(a, b, c) __builtin_amdgcn_mfma_f32_16x16x16f16(a, b, c, 0, 0, 0)
#endif
#define EXP2 __builtin_amdgcn_exp2f
#define LOG2 __builtin_amdgcn_logf
#define RCPF __builtin_amdgcn_rcpf

__device__ __forceinline__ f32x2 pfma(f32x2 a, f32x2 b, f32x2 c) {
  return __builtin_elementwise_fma(a, b, c);
}

__device__ __forceinline__ const f32x4* film_base(const unsigned char* smem, int l, int qd) {
  return (const f32x4*)(smem + FILM2_OFF + ((l * 16 + qd) << 6));
}

// FiLM (+softplus, log2-domain) on a D-quad; acc includes (prescaled) bias.
// acc = L2E*pre; returns h~ = log2(1+2^(L2E*v)) packed f16x4 (= next B operand).
template<bool SP>
__device__ __forceinline__ f16x4 film_quad(f32x4 acc, float ctx,
                                           f32x4 wscq, f32x4 bscq, f32x4 wshq) {
  f32x2 ctx2 = {ctx, ctx};
  f32x2 one = {1.f, 1.f};
  f32x2 z0 = pfma(ctx2, (f32x2){wscq.x, wscq.y}, (f32x2){bscq.x, bscq.y});
  f32x2 z1 = pfma(ctx2, (f32x2){wscq.z, wscq.w}, (f32x2){bscq.z, bscq.w});
  f32x2 d0 = {EXP2(-z0.x), EXP2(-z0.y)};  d0 += one;
  f32x2 d1 = {EXP2(-z1.x), EXP2(-z1.y)};  d1 += one;
  f32x2 s0 = {RCPF(d0.x), RCPF(d0.y)};
  f32x2 s1 = {RCPF(d1.x), RCPF(d1.y)};
  f32x2 v0 = pfma(ctx2, (f32x2){wshq.x, wshq.y}, s0 * (f32x2){acc.x, acc.y});
  f32x2 v1 = pfma(ctx2, (f32x2){wshq.z, wshq.w}, s1 * (f32x2){acc.z, acc.w});
  if (SP) {  // h~ = log2(1 + 2^v~)
    f32x2 u0 = {EXP2(v0.x), EXP2(v0.y)};  u0 += one;
    f32x2 u1 = {EXP2(v1.x), EXP2(v1.y)};  u1 += one;
    v0 = (f32x2){LOG2(u0.x), LOG2(u0.y)};
    v1 = (f32x2){LOG2(u1.x), LOG2(u1.y)};
  }
  auto p01 = __builtin_amdgcn_cvt_pkrtz(v0.x, v0.y);
  auto p23 = __builtin_amdgcn_cvt_pkrtz(v1.x, v1.y);
  u32x2 w;
  w.x = __builtin_bit_cast(unsigned int, p01);
  w.y = __builtin_bit_cast(unsigned int, p23);
  return __builtin_bit_cast(f16x4, w);
}

__device__ __forceinline__ f16x4 a_tile(const unsigned char* smem, int aoff,
                                        int m, int t, int lane) {
  return *(const f16x4*)(smem + aoff + (((m * 4 + t) * 64 + lane) << 3));
}

// ============ prep kernel: one block per b, builds ws images ============
__global__ __launch_bounds__(512)
void ode_prep_kernel(const float* __restrict__ tnw, unsigned char* __restrict__ ws) {
  const int b = blockIdx.x;
  const int tid = threadIdx.x;
  const float* __restrict__ wb = tnw + (size_t)b * TOTAL_W;
  unsigned char* __restrict__ wsb = ws + (size_t)b * WSB;

  // film2 params; layer l: bias@bo, wsc@bo+d, bsc@bo+2d, wsh@bo+3d
  // Prescale: wsc,bsc by L2E (all l); bias,wsh by L2E for l<3 (log2-domain fold).
  if (tid < 64) {
    const int biaso[4] = {192, 4544, 8896, 9344};
    const int dim[4] = {64, 64, 64, 3};
#pragma unroll
    for (int l = 0; l < 4; ++l) {
      float bv = 0.f, wscv = 0.f, bscv = 0.f, wshv = 0.f;
      if (tid < dim[l]) {
        int bo = biaso[l], d = dim[l];
        float bs = (l < 3) ? L2E : 1.0f;
        bv = wb[bo + tid] * bs;
        wscv = wb[bo + d + tid] * L2E;
        bscv = wb[bo + 2 * d + tid] * L2E;
        wshv = wb[bo + 3 * d + tid] * bs;
      }
      float* f2 = (float*)(wsb + WS_FILM + ((l * 16 + (tid >> 2)) << 6)) + (tid & 3);
      f2[0] = bv;
      f2[4] = wscv;
      f2[8] = bscv;
      f2[12] = wshv;
    }
  }
  // A-tiles L1/L2 (A = W^T, 16x16), UNSCALED (L2E*LN2 = 1 folds away)
#pragma unroll
  for (int L = 0; L < 2; ++L) {
    const int woff = L ? 4800 : 448;
    unsigned char* dst = wsb + (L ? WS_A2 : WS_A1);
#pragma unroll
    for (int it = 0; it < 2; ++it) {
      int idx = tid + it * 512;          // < 1024
      int lane = idx & 63;
      int tile = idx >> 6;               // m*4 + t
      int m = tile >> 2, t = tile & 3;
      int f_out = 16 * m + (lane & 15);
      int f_in0 = 16 * t + 4 * (lane >> 4);
      f16x4 h;
#pragma unroll
      for (int i = 0; i < 4; ++i) h[i] = (_Float16)wb[woff + (f_in0 + i) * 64 + f_out];
      *(f16x4*)(dst + idx * 8) = h;
    }
  }
  // A0 tile image [m][lane], scaled by L2E
  if (tid < 256) {
    int m = tid >> 6;
    int lane = tid & 63;
    int kg = lane >> 4, row = lane & 15;
    f16x4 h = {0, 0, 0, 0};
    if (kg == 0) {
#pragma unroll
      for (int i = 0; i < 3; ++i) h[i] = (_Float16)(wb[i * 64 + 16 * m + row] * L2E);
    }
    *(f16x4*)(wsb + WS_A0 + tid * 8) = h;
  }
  // A3 tile image [t][lane], scaled by LN2 (consumes log2-domain h~)
  if (tid < 256) {
    int t = tid >> 6;
    int lane = tid & 63;
    int kg = lane >> 4, row = lane & 15;
    f16x4 h = {0, 0, 0, 0};
    if (row < 3) {
#pragma unroll
      for (int i = 0; i < 4; ++i)
        h[i] = (_Float16)(wb[9152 + (16 * t + 4 * kg + i) * 3 + row] * LN2);
    }
    *(f16x4*)(wsb + WS_A3 + tid * 8) = h;
  }
}

// ============ main kernel ============
__global__ __launch_bounds__(256)
void ode_hypernet_kernel(const float* __restrict__ context,
                         const float* __restrict__ y,
                         const unsigned char* __restrict__ ws,
                         float* __restrict__ out) {
  __shared__ __align__(16) unsigned char smem[LDS_BYTES];
  const int b = blockIdx.y;
  const int tid = threadIdx.x;
  const unsigned char* __restrict__ wsb = ws + (size_t)b * WSB;

  const int lane = tid & 63;
  const int wid = tid >> 6;
  const int g = lane >> 4;
  const int col = lane & 15;

  // ---------- staging: linear coalesced copy of film2+A1+A2 (20 KB) ----------
#pragma unroll
  for (int it = 0; it < 5; ++it) {
    int i = tid + it * 256;  // i < 1280
    *(f32x4*)(smem + i * 16) = *(const f32x4*)(wsb + i * 16);
  }
  f16x4 A0r[4], A3r[4];
#pragma unroll
  for (int m = 0; m < 4; ++m)
    A0r[m] = *(const f16x4*)(wsb + WS_A0 + ((m * 64 + lane) << 3));
#pragma unroll
  for (int t = 0; t < 4; ++t)
    A3r[t] = *(const f16x4*)(wsb + WS_A3 + ((t * 64 + lane) << 3));
  __syncthreads();

  // ---------- per-wave main: 4 point-groups pipelined per layer ----------
  const int pt0 = wid * 32 + col;  // 0..127
  const int nb = blockIdx.x * 256;
  const size_t cb = (size_t)b * NN;

  float ctxs[4];
  f16x4 By[4];
#pragma unroll
  for (int k = 0; k < 4; ++k) {  // group k -> point nb + (k>>1)*128 + pt0 + (k&1)*16
    int n = nb + (k >> 1) * 128 + pt0 + (k & 1) * 16;
    ctxs[k] = context[cb + n];
    const float* yp = y + (cb + n) * 3;
    f16x4 v = {0, 0, 0, 0};
    if (g == 0) {
      v[0] = (_Float16)yp[0];
      v[1] = (_Float16)yp[1];
      v[2] = (_Float16)yp[2];
    }
    By[k] = v;
  }

  f16x4 Bc[4][4], Bd[4][4];  // [group][tile]

  // ----- layer 0 (3 -> 64): one K=16 MFMA per (m, group) -----
#pragma unroll
  for (int m = 0; m < 4; ++m) {
    const f32x4* fb = film_base(smem, 0, 4 * m + g);
    f32x4 biasq = fb[0], wscq = fb[1], bscq = fb[2], wshq = fb[3];
#pragma unroll
    for (int k = 0; k < 4; ++k) {
      f32x4 c = biasq;
      c = MFMAK16(A0r[m], By[k], c);
      Bc[k][m] = film_quad<true>(c, ctxs[k], wscq, bscq, wshq);
    }
  }

  // ----- layer 1 (64 -> 64): Bc -> Bd -----
#pragma unroll
  for (int m = 0; m < 4; ++m) {
    const f32x4* fb = film_base(smem, 1, 4 * m + g);
    f32x4 biasq = fb[0], wscq = fb[1], bscq = fb[2], wshq = fb[3];
    f16x4 a[4];
#pragma unroll
    for (int t = 0; t < 4; ++t) a[t] = a_tile(smem, A1_OFF, m, t, lane);
#pragma unroll
    for (int k = 0; k < 4; ++k) {
      f32x4 c = biasq;
#pragma unroll
      for (int t = 0; t < 4; ++t) c = MFMAK16(a[t], Bc[k][t], c);
      Bd[k][m] = film_quad<true>(c, ctxs[k], wscq, bscq, wshq);
    }
  }

  // ----- layer 2 (64 -> 64): Bd -> Bc -----
#pragma unroll
  for (int m = 0; m < 4; ++m) {
    const f32x4* fb = film_base(smem, 2, 4 * m + g);
    f32x4 biasq = fb[0], wscq = fb[1], bscq = fb[2], wshq = fb[3];
    f16x4 a[4];
#pragma unroll
    for (int t = 0; t < 4; ++t) a[t] = a_tile(smem, A2_OFF, m, t, lane);
#pragma unroll
    for (int k = 0; k < 4; ++k) {
      f32x4 c = biasq;
#pragma unroll
      for (int t = 0; t < 4; ++t) c = MFMAK16(a[t], Bd[k][t], c);
      Bc[k][m] = film_quad<true>(c, ctxs[k], wscq, bscq, wshq);
    }
  }

  // ----- layer 3 (64 -> 3): A from regs (LN2-prescaled), FiLM only -----
  {
    const f32x4* fb = film_base(smem, 3, g);
    f32x4 biasq = fb[0], wscq = fb[1], bscq = fb[2], wshq = fb[3];
#pragma unroll
    for (int k = 0; k < 4; ++k) {
      f32x4 c = biasq;
#pragma unroll
      for (int t = 0; t < 4; ++t) c = MFMAK16(A3r[t], Bc[k][t], c);
      if (g == 0) {
        int n = nb + (k >> 1) * 128 + pt0 + (k & 1) * 16;
        float ctx = ctxs[k];
#pragma unroll
        for (int j = 0; j < 3; ++j) {
          float z = fmaf(ctx, wscq[j], bscq[j]);
          float s = RCPF(1.0f + EXP2(-z));
          float v = fmaf(ctx, wshq[j], s * c[j]);
          out[((size_t)b * NN + n) * 3 + j] = v;
        }
      }
    }
  }
}

extern "C" void kernel_launch(void* const* d_in, const int* in_sizes, int n_in,
                              void* d_out, int out_size, void* d_ws, size_t ws_size,
                              hipStream_t stream) {
  const float* context = (const float*)d_in[0];  // (64, 8192)
  const float* y       = (const float*)d_in[1];  // (64, 8192, 3)
  const float* tnw     = (const float*)d_in[2];  // (64, 9356)
  float* out           = (float*)d_out;          // (64, 8192, 3)
  unsigned char* ws    = (unsigned char*)d_ws;   // needs 64*24576 = 1,572,864 B

  ode_prep_kernel<<<dim3(BB, 1, 1), dim3(512, 1, 1), 0, stream>>>(tnw, ws);
  dim3 grid(NN / 256, BB, 1);  // 2048 blocks, 256 points each (one pass)
  dim3 block(256, 1, 1);
  ode_hypernet_kernel<<<grid, block, 0, stream>>>(context, y, ws, out);
}